// Round 1
// baseline (1619.610 us; speedup 1.0000x reference)
//
#include <hip/hip_runtime.h>
#include <hip/hip_bf16.h>

// ValueNet: 7x SAGEConv(mean) + global_add_pool + MLP head.
// N=50000 nodes, E=600000 edges/set, H=128, G=64 graphs. All fp32.

constexpr int N_NODES = 50000;
constexpr int NE      = 600000;
constexpr int H       = 128;
constexpr int NG      = 64;

// ---------------- CSR build (counting sort by dst) ----------------

__global__ void k_count(const int* __restrict__ dst, int* __restrict__ cnt) {
    int e = blockIdx.x * blockDim.x + threadIdx.x;
    if (e < NE) atomicAdd(&cnt[dst[e]], 1);
}

// single block, 1024 threads: exclusive scan of counts -> ptr, and fill=ptr copy
__global__ void k_scan(const int* __restrict__ counts, int* __restrict__ ptr,
                       int* __restrict__ fill) {
    __shared__ int sh[1024];
    const int CH = (N_NODES + 1023) / 1024;  // 49
    int t = threadIdx.x;
    int base = t * CH;
    int s = 0;
    for (int j = 0; j < CH; ++j) {
        int i = base + j;
        if (i < N_NODES) s += counts[i];
    }
    sh[t] = s;
    __syncthreads();
    for (int off = 1; off < 1024; off <<= 1) {
        int v = 0;
        if (t >= off) v = sh[t - off];
        __syncthreads();
        if (t >= off) sh[t] += v;
        __syncthreads();
    }
    int run = sh[t] - s;  // exclusive prefix
    for (int j = 0; j < CH; ++j) {
        int i = base + j;
        if (i < N_NODES) {
            int c = counts[i];   // read BEFORE overwrite (fill may alias counts)
            ptr[i]  = run;
            fill[i] = run;
            run += c;
        }
    }
    if (t == 1023) ptr[N_NODES] = sh[1023];
}

__global__ void k_build(const int* __restrict__ src, const int* __restrict__ dst,
                        int* __restrict__ fill, int* __restrict__ adj) {
    int e = blockIdx.x * blockDim.x + threadIdx.x;
    if (e < NE) {
        int pos = atomicAdd(&fill[dst[e]], 1);
        adj[pos] = src[e];
    }
}

// ---------------- mean aggregation: one wave per node ----------------

__global__ __launch_bounds__(256) void k_agg(const float* __restrict__ h,
                                             const int* __restrict__ ptr,
                                             const int* __restrict__ adj,
                                             float* __restrict__ agg) {
    int w    = (blockIdx.x * blockDim.x + threadIdx.x) >> 6;  // node id
    int lane = threadIdx.x & 63;
    if (w >= N_NODES) return;
    int beg = ptr[w], end = ptr[w + 1];
    float ax = 0.f, ay = 0.f;
    for (int e = beg; e < end; ++e) {
        int nb = adj[e];  // wave-uniform
        float2 v = *(const float2*)(h + (size_t)nb * H + lane * 2);
        ax += v.x; ay += v.y;
    }
    int deg = end - beg;
    float inv = 1.0f / (float)(deg > 1 ? deg : 1);
    float2 o; o.x = ax * inv; o.y = ay * inv;
    *(float2*)(agg + (size_t)w * H + lane * 2) = o;
}

// ---------------- fused SAGE GEMM: out = agg@Wl + x@Wr + bl, optional L2-norm ----------------
// Block: 256 thr. Tile: 64 rows x 128 cols. Thread: 8 rows x 4 cols.

constexpr int BM = 64;
constexpr int KB = 8;

__global__ __launch_bounds__(256) void k_gemm(const float* __restrict__ Aagg,
                                              const float* __restrict__ Ax,
                                              const float* __restrict__ Wl,
                                              const float* __restrict__ Wr,
                                              const float* __restrict__ bl,
                                              float* __restrict__ out, int norm) {
    __shared__ float Ash[KB][BM + 8];  // stride 72 floats -> 16B aligned rows
    __shared__ float Wsh[KB][H];

    int tid  = threadIdx.x;
    int tcol = tid & 31;   // cols tcol*4 .. +3
    int trow = tid >> 5;   // rows trow*8 .. +7
    int rowBase = blockIdx.x * BM;

    float acc[8][4];
#pragma unroll
    for (int i = 0; i < 8; ++i)
#pragma unroll
        for (int j = 0; j < 4; ++j) acc[i][j] = 0.f;

    int lr = tid >> 2;           // 0..63 A-load row
    int lk = (tid & 3) * 2;      // 0,2,4,6 A-load k pair
    int grow = rowBase + lr;
    if (grow > N_NODES - 1) grow = N_NODES - 1;
    int wk = tid >> 5;           // 0..7 W-load k
    int wc = (tid & 31) * 4;     // W-load col

    for (int phase = 0; phase < 2; ++phase) {
        const float* A = phase ? Ax : Aagg;
        const float* W = phase ? Wr : Wl;
        for (int kb = 0; kb < H; kb += KB) {
            __syncthreads();
            float2 av = *(const float2*)(A + (size_t)grow * H + kb + lk);
            Ash[lk][lr]     = av.x;
            Ash[lk + 1][lr] = av.y;
            *(float4*)&Wsh[wk][wc] = *(const float4*)(W + (size_t)(kb + wk) * H + wc);
            __syncthreads();
#pragma unroll
            for (int kk = 0; kk < KB; ++kk) {
                float4 a0 = *(const float4*)&Ash[kk][trow * 8];
                float4 a1 = *(const float4*)&Ash[kk][trow * 8 + 4];
                float4 w  = *(const float4*)&Wsh[kk][tcol * 4];
                float av8[8] = {a0.x, a0.y, a0.z, a0.w, a1.x, a1.y, a1.z, a1.w};
#pragma unroll
                for (int i = 0; i < 8; ++i) {
                    acc[i][0] += av8[i] * w.x;
                    acc[i][1] += av8[i] * w.y;
                    acc[i][2] += av8[i] * w.z;
                    acc[i][3] += av8[i] * w.w;
                }
            }
        }
    }

    float4 bv = *(const float4*)(bl + tcol * 4);
#pragma unroll
    for (int i = 0; i < 8; ++i) {
        acc[i][0] += bv.x; acc[i][1] += bv.y; acc[i][2] += bv.z; acc[i][3] += bv.w;
    }

    if (norm) {
#pragma unroll
        for (int i = 0; i < 8; ++i) {
            float ss = acc[i][0] * acc[i][0] + acc[i][1] * acc[i][1] +
                       acc[i][2] * acc[i][2] + acc[i][3] * acc[i][3];
#pragma unroll
            for (int m = 1; m < 32; m <<= 1) ss += __shfl_xor(ss, m, 64);
            float inv = 1.0f / fmaxf(sqrtf(ss), 1e-12f);
            acc[i][0] *= inv; acc[i][1] *= inv; acc[i][2] *= inv; acc[i][3] *= inv;
        }
    }

#pragma unroll
    for (int i = 0; i < 8; ++i) {
        int r = rowBase + trow * 8 + i;
        if (r < N_NODES) {
            *(float4*)(out + (size_t)r * H + tcol * 4) =
                make_float4(acc[i][0], acc[i][1], acc[i][2], acc[i][3]);
        }
    }
}

// ---------------- global add pool (batch is sorted) ----------------

constexpr int POOL_ROWS = 256;

__global__ void k_pool(const float* __restrict__ h, const int* __restrict__ batch,
                       float* __restrict__ g) {
    int col = threadIdx.x;  // 0..127
    int r0 = blockIdx.x * POOL_ROWS;
    int r1 = r0 + POOL_ROWS;
    if (r1 > N_NODES) r1 = N_NODES;
    if (r0 >= N_NODES) return;
    float acc = 0.f;
    int cur = batch[r0];
    for (int r = r0; r < r1; ++r) {
        int b = batch[r];
        if (b != cur) {
            atomicAdd(&g[cur * H + col], acc);
            acc = 0.f;
            cur = b;
        }
        acc += h[(size_t)r * H + col];
    }
    atomicAdd(&g[cur * H + col], acc);
}

// ---------------- MLP head: relu(g@W0+b0) -> relu(@W1+b1) -> @Wh+bh ----------------

__global__ void k_mlp(const float* __restrict__ g, const float* __restrict__ W0,
                      const float* __restrict__ b0, const float* __restrict__ W1,
                      const float* __restrict__ b1, const float* __restrict__ Wh,
                      const float* __restrict__ bh, float* __restrict__ out) {
    int gi = blockIdx.x;
    int t  = threadIdx.x;  // 0..127
    __shared__ float buf0[H];
    __shared__ float buf1[H];
    __shared__ float red[2];

    float acc = b0[t];
    for (int k = 0; k < H; ++k) acc += g[gi * H + k] * W0[k * H + t];
    buf0[t] = fmaxf(acc, 0.f);
    __syncthreads();

    acc = b1[t];
    for (int k = 0; k < H; ++k) acc += buf0[k] * W1[k * H + t];
    buf1[t] = fmaxf(acc, 0.f);
    __syncthreads();

    float p = buf1[t] * Wh[t];
    for (int m = 1; m < 64; m <<= 1) p += __shfl_xor(p, m, 64);
    if ((t & 63) == 0) red[t >> 6] = p;
    __syncthreads();
    if (t == 0) out[gi] = red[0] + red[1] + bh[0];
}

// ---------------- driver ----------------

extern "C" void kernel_launch(void* const* d_in, const int* in_sizes, int n_in,
                              void* d_out, int out_size, void* d_ws, size_t ws_size,
                              hipStream_t stream) {
    const float* x     = (const float*)d_in[0];
    const int*   eic   = (const int*)d_in[1];
    const int*   eid   = (const int*)d_in[2];
    const int*   eit   = (const int*)d_in[3];
    const int*   batch = (const int*)d_in[4];
    // conv weights: c{1..5}_{Wl,bl,Wr} at indices 5..19
    const float* cW[5][3];
    for (int c = 0; c < 5; ++c) {
        cW[c][0] = (const float*)d_in[5 + c * 3 + 0];  // Wl
        cW[c][1] = (const float*)d_in[5 + c * 3 + 1];  // bl
        cW[c][2] = (const float*)d_in[5 + c * 3 + 2];  // Wr
    }
    const float* l0_W = (const float*)d_in[20];
    const float* l0_b = (const float*)d_in[21];
    const float* l1_W = (const float*)d_in[22];
    const float* l1_b = (const float*)d_in[23];
    const float* hd_W = (const float*)d_in[24];
    const float* hd_b = (const float*)d_in[25];
    float* outp = (float*)d_out;

    // workspace carve-up
    const size_t NH = (size_t)N_NODES * H;
    float* bufA = (float*)d_ws;
    float* bufB = bufA + NH;
    float* aggb = bufB + NH;
    float* gbuf = aggb + NH;
    int* iws  = (int*)(gbuf + (size_t)NG * H);
    int* ptr0 = iws;                       // eic CSR
    int* ptr1 = ptr0 + (N_NODES + 1);      // eid CSR
    int* ptr2 = ptr1 + (N_NODES + 1);      // eit CSR
    int* adj0 = ptr2 + (N_NODES + 1);
    int* adj1 = adj0 + NE;
    int* adj2 = adj1 + NE;
    int* fill = adj2 + NE;

    const int* esrc[3] = {eic, eid, eit};
    int* ptrs[3] = {ptr0, ptr1, ptr2};
    int* adjs[3] = {adj0, adj1, adj2};

    dim3 b256(256);
    dim3 gE((NE + 255) / 256);

    // build 3 CSRs (dst-sorted)
    for (int s = 0; s < 3; ++s) {
        hipMemsetAsync(fill, 0, N_NODES * sizeof(int), stream);
        k_count<<<gE, b256, 0, stream>>>(esrc[s] + NE, fill);
        k_scan<<<1, 1024, 0, stream>>>(fill, ptrs[s], fill);
        k_build<<<gE, b256, 0, stream>>>(esrc[s], esrc[s] + NE, fill, adjs[s]);
    }

    // layer schedule: {csr set, conv idx, norm}
    // sets: 0=eic, 1=eid, 2=eit; convs 0-based
    const int L_set[7]  = {1, 0, 0, 2, 1, 0, 0};
    const int L_conv[7] = {0, 1, 1, 2, 3, 4, 4};
    const int L_norm[7] = {1, 1, 1, 0, 1, 1, 1};

    dim3 gAgg((N_NODES + 3) / 4);           // 4 waves/block, 1 wave/node
    dim3 gGemm((N_NODES + BM - 1) / BM);    // 782

    const float* hin = x;
    float* bufs[2] = {bufA, bufB};
    for (int L = 0; L < 7; ++L) {
        float* hout = bufs[L & 1];
        int s = L_set[L], c = L_conv[L];
        k_agg<<<gAgg, b256, 0, stream>>>(hin, ptrs[s], adjs[s], aggb);
        k_gemm<<<gGemm, b256, 0, stream>>>(aggb, hin, cW[c][0], cW[c][2], cW[c][1],
                                           hout, L_norm[L]);
        hin = hout;
    }

    // pool + MLP
    hipMemsetAsync(gbuf, 0, (size_t)NG * H * sizeof(float), stream);
    k_pool<<<dim3((N_NODES + POOL_ROWS - 1) / POOL_ROWS), dim3(H), 0, stream>>>(
        hin, batch, gbuf);
    k_mlp<<<dim3(NG), dim3(H), 0, stream>>>(gbuf, l0_W, l0_b, l1_W, l1_b, hd_W, hd_b,
                                            outp);
}

// Round 2
// 1124.326 us; speedup vs baseline: 1.4405x; 1.4405x over previous
//
#include <hip/hip_runtime.h>
#include <hip/hip_bf16.h>

// ValueNet: 7x SAGEConv(mean) + global_add_pool + MLP head.
// N=50000 nodes, E=600000 edges/set, H=128, G=64 graphs. All fp32.

constexpr int N_NODES = 50000;
constexpr int NE      = 600000;
constexpr int H       = 128;
constexpr int NG      = 64;

// ---------------- CSR build (counting sort by dst) ----------------

__global__ void k_count(const int* __restrict__ dst, int* __restrict__ cnt) {
    int e = blockIdx.x * blockDim.x + threadIdx.x;
    if (e < NE) atomicAdd(&cnt[dst[e]], 1);
}

// hierarchical exclusive scan of counts -> ptr (and fill = ptr copy)
constexpr int SCAN_B = 256;
constexpr int SCAN_G = (N_NODES + SCAN_B - 1) / SCAN_B;  // 196

__global__ void k_bsum(const int* __restrict__ cnt, int* __restrict__ bsum) {
    __shared__ int sh[SCAN_B];
    int t = threadIdx.x;
    int i = blockIdx.x * SCAN_B + t;
    sh[t] = (i < N_NODES) ? cnt[i] : 0;
    __syncthreads();
    for (int off = SCAN_B / 2; off > 0; off >>= 1) {
        if (t < off) sh[t] += sh[t + off];
        __syncthreads();
    }
    if (t == 0) bsum[blockIdx.x] = sh[0];
}

__global__ void k_bscan(int* bsum, int* ptr) {  // 1 block, 256 threads
    __shared__ int sh[SCAN_B];
    int t = threadIdx.x;
    int v = (t < SCAN_G) ? bsum[t] : 0;
    sh[t] = v;
    __syncthreads();
    for (int off = 1; off < SCAN_B; off <<= 1) {
        int u = (t >= off) ? sh[t - off] : 0;
        __syncthreads();
        if (t >= off) sh[t] += u;
        __syncthreads();
    }
    if (t < SCAN_G) bsum[t] = sh[t] - v;  // exclusive block offsets
    if (t == 0) ptr[N_NODES] = sh[SCAN_B - 1];  // total (= NE)
}

__global__ void k_bwrite(const int* cnt, const int* __restrict__ boff,
                         int* __restrict__ ptr, int* fill) {
    __shared__ int sh[SCAN_B];
    int t = threadIdx.x;
    int i = blockIdx.x * SCAN_B + t;
    int v = (i < N_NODES) ? cnt[i] : 0;
    sh[t] = v;
    __syncthreads();
    for (int off = 1; off < SCAN_B; off <<= 1) {
        int u = (t >= off) ? sh[t - off] : 0;
        __syncthreads();
        if (t >= off) sh[t] += u;
        __syncthreads();
    }
    int excl = sh[t] - v + boff[blockIdx.x];
    if (i < N_NODES) {
        ptr[i]  = excl;
        fill[i] = excl;
    }
}

__global__ void k_build(const int* __restrict__ src, const int* __restrict__ dst,
                        int* __restrict__ fill, int* __restrict__ adj) {
    int e = blockIdx.x * blockDim.x + threadIdx.x;
    if (e < NE) {
        int pos = atomicAdd(&fill[dst[e]], 1);
        adj[pos] = src[e];
    }
}

// ---------------- mean aggregation ----------------
// One wave handles 2 nodes: lanes 0-31 -> node 2w, lanes 32-63 -> node 2w+1.
// Each 32-lane half reads a full 512B row per neighbor (float4/lane).
// Neighbor indices preloaded 32 at a time (one coalesced load), broadcast via
// __shfl(width=32); gather loop unrolled 4-wide for 4 loads in flight.

__global__ __launch_bounds__(256) void k_agg(const float* __restrict__ h,
                                             const int* __restrict__ ptr,
                                             const int* __restrict__ adj,
                                             float* __restrict__ agg) {
    int wid  = (blockIdx.x * blockDim.x + threadIdx.x) >> 6;
    int lane = threadIdx.x & 63;
    int sl   = lane & 31;
    int node = wid * 2 + (lane >> 5);
    if (node >= N_NODES) return;
    int beg = ptr[node], end = ptr[node + 1];
    int deg = end - beg;
    const float* hrow = h + sl * 4;
    float ax = 0.f, ay = 0.f, az = 0.f, aw = 0.f;
    for (int base = 0; base < deg; base += 32) {
        int m = deg - base;
        if (m > 32) m = 32;
        int idx = (sl < m) ? adj[beg + base + sl] : 0;
        int j = 0;
        for (; j + 4 <= m; j += 4) {
            int n0 = __shfl(idx, j,     32);
            int n1 = __shfl(idx, j + 1, 32);
            int n2 = __shfl(idx, j + 2, 32);
            int n3 = __shfl(idx, j + 3, 32);
            float4 v0 = *(const float4*)(hrow + (size_t)n0 * H);
            float4 v1 = *(const float4*)(hrow + (size_t)n1 * H);
            float4 v2 = *(const float4*)(hrow + (size_t)n2 * H);
            float4 v3 = *(const float4*)(hrow + (size_t)n3 * H);
            ax += (v0.x + v1.x) + (v2.x + v3.x);
            ay += (v0.y + v1.y) + (v2.y + v3.y);
            az += (v0.z + v1.z) + (v2.z + v3.z);
            aw += (v0.w + v1.w) + (v2.w + v3.w);
        }
        for (; j < m; ++j) {
            int n0 = __shfl(idx, j, 32);
            float4 v0 = *(const float4*)(hrow + (size_t)n0 * H);
            ax += v0.x; ay += v0.y; az += v0.z; aw += v0.w;
        }
    }
    float inv = 1.0f / (float)(deg > 1 ? deg : 1);
    *(float4*)(agg + (size_t)node * H + sl * 4) =
        make_float4(ax * inv, ay * inv, az * inv, aw * inv);
}

// ---------------- fused SAGE GEMM: out = agg@Wl + x@Wr + bl, optional L2-norm ----------------
// Block: 256 thr. Tile: 64 rows x 128 cols. Thread: 8 rows x 4 cols.

constexpr int BM = 64;
constexpr int KB = 8;

__global__ __launch_bounds__(256) void k_gemm(const float* __restrict__ Aagg,
                                              const float* __restrict__ Ax,
                                              const float* __restrict__ Wl,
                                              const float* __restrict__ Wr,
                                              const float* __restrict__ bl,
                                              float* __restrict__ out, int norm) {
    __shared__ float Ash[KB][BM + 8];
    __shared__ float Wsh[KB][H];

    int tid  = threadIdx.x;
    int tcol = tid & 31;   // cols tcol*4 .. +3
    int trow = tid >> 5;   // rows trow*8 .. +7
    int rowBase = blockIdx.x * BM;

    float acc[8][4];
#pragma unroll
    for (int i = 0; i < 8; ++i)
#pragma unroll
        for (int j = 0; j < 4; ++j) acc[i][j] = 0.f;

    int lr = tid >> 2;           // 0..63 A-load row
    int lk = (tid & 3) * 2;      // 0,2,4,6 A-load k pair
    int grow = rowBase + lr;
    if (grow > N_NODES - 1) grow = N_NODES - 1;
    int wk = tid >> 5;           // 0..7 W-load k
    int wc = (tid & 31) * 4;     // W-load col

    for (int phase = 0; phase < 2; ++phase) {
        const float* A = phase ? Ax : Aagg;
        const float* W = phase ? Wr : Wl;
        for (int kb = 0; kb < H; kb += KB) {
            __syncthreads();
            float2 av = *(const float2*)(A + (size_t)grow * H + kb + lk);
            Ash[lk][lr]     = av.x;
            Ash[lk + 1][lr] = av.y;
            *(float4*)&Wsh[wk][wc] = *(const float4*)(W + (size_t)(kb + wk) * H + wc);
            __syncthreads();
#pragma unroll
            for (int kk = 0; kk < KB; ++kk) {
                float4 a0 = *(const float4*)&Ash[kk][trow * 8];
                float4 a1 = *(const float4*)&Ash[kk][trow * 8 + 4];
                float4 w  = *(const float4*)&Wsh[kk][tcol * 4];
                float av8[8] = {a0.x, a0.y, a0.z, a0.w, a1.x, a1.y, a1.z, a1.w};
#pragma unroll
                for (int i = 0; i < 8; ++i) {
                    acc[i][0] += av8[i] * w.x;
                    acc[i][1] += av8[i] * w.y;
                    acc[i][2] += av8[i] * w.z;
                    acc[i][3] += av8[i] * w.w;
                }
            }
        }
    }

    float4 bv = *(const float4*)(bl + tcol * 4);
#pragma unroll
    for (int i = 0; i < 8; ++i) {
        acc[i][0] += bv.x; acc[i][1] += bv.y; acc[i][2] += bv.z; acc[i][3] += bv.w;
    }

    if (norm) {
#pragma unroll
        for (int i = 0; i < 8; ++i) {
            float ss = acc[i][0] * acc[i][0] + acc[i][1] * acc[i][1] +
                       acc[i][2] * acc[i][2] + acc[i][3] * acc[i][3];
#pragma unroll
            for (int m = 1; m < 32; m <<= 1) ss += __shfl_xor(ss, m, 64);
            float inv = 1.0f / fmaxf(sqrtf(ss), 1e-12f);
            acc[i][0] *= inv; acc[i][1] *= inv; acc[i][2] *= inv; acc[i][3] *= inv;
        }
    }

#pragma unroll
    for (int i = 0; i < 8; ++i) {
        int r = rowBase + trow * 8 + i;
        if (r < N_NODES) {
            *(float4*)(out + (size_t)r * H + tcol * 4) =
                make_float4(acc[i][0], acc[i][1], acc[i][2], acc[i][3]);
        }
    }
}

// ---------------- global add pool (batch is sorted) ----------------

constexpr int POOL_ROWS = 256;

__global__ void k_pool(const float* __restrict__ h, const int* __restrict__ batch,
                       float* __restrict__ g) {
    int col = threadIdx.x;  // 0..127
    int r0 = blockIdx.x * POOL_ROWS;
    int r1 = r0 + POOL_ROWS;
    if (r1 > N_NODES) r1 = N_NODES;
    if (r0 >= N_NODES) return;
    float acc = 0.f;
    int cur = batch[r0];
    for (int r = r0; r < r1; ++r) {
        int b = batch[r];
        if (b != cur) {
            atomicAdd(&g[cur * H + col], acc);
            acc = 0.f;
            cur = b;
        }
        acc += h[(size_t)r * H + col];
    }
    atomicAdd(&g[cur * H + col], acc);
}

// ---------------- MLP head ----------------

__global__ void k_mlp(const float* __restrict__ g, const float* __restrict__ W0,
                      const float* __restrict__ b0, const float* __restrict__ W1,
                      const float* __restrict__ b1, const float* __restrict__ Wh,
                      const float* __restrict__ bh, float* __restrict__ out) {
    int gi = blockIdx.x;
    int t  = threadIdx.x;  // 0..127
    __shared__ float buf0[H];
    __shared__ float buf1[H];
    __shared__ float red[2];

    float acc = b0[t];
    for (int k = 0; k < H; ++k) acc += g[gi * H + k] * W0[k * H + t];
    buf0[t] = fmaxf(acc, 0.f);
    __syncthreads();

    acc = b1[t];
    for (int k = 0; k < H; ++k) acc += buf0[k] * W1[k * H + t];
    buf1[t] = fmaxf(acc, 0.f);
    __syncthreads();

    float p = buf1[t] * Wh[t];
    for (int m = 1; m < 64; m <<= 1) p += __shfl_xor(p, m, 64);
    if ((t & 63) == 0) red[t >> 6] = p;
    __syncthreads();
    if (t == 0) out[gi] = red[0] + red[1] + bh[0];
}

// ---------------- driver ----------------

extern "C" void kernel_launch(void* const* d_in, const int* in_sizes, int n_in,
                              void* d_out, int out_size, void* d_ws, size_t ws_size,
                              hipStream_t stream) {
    const float* x     = (const float*)d_in[0];
    const int*   eic   = (const int*)d_in[1];
    const int*   eid   = (const int*)d_in[2];
    const int*   eit   = (const int*)d_in[3];
    const int*   batch = (const int*)d_in[4];
    const float* cW[5][3];
    for (int c = 0; c < 5; ++c) {
        cW[c][0] = (const float*)d_in[5 + c * 3 + 0];  // Wl
        cW[c][1] = (const float*)d_in[5 + c * 3 + 1];  // bl
        cW[c][2] = (const float*)d_in[5 + c * 3 + 2];  // Wr
    }
    const float* l0_W = (const float*)d_in[20];
    const float* l0_b = (const float*)d_in[21];
    const float* l1_W = (const float*)d_in[22];
    const float* l1_b = (const float*)d_in[23];
    const float* hd_W = (const float*)d_in[24];
    const float* hd_b = (const float*)d_in[25];
    float* outp = (float*)d_out;

    // workspace carve-up
    const size_t NH = (size_t)N_NODES * H;
    float* bufA = (float*)d_ws;
    float* bufB = bufA + NH;
    float* aggb = bufB + NH;
    float* gbuf = aggb + NH;
    int* iws  = (int*)(gbuf + (size_t)NG * H);
    int* ptr0 = iws;
    int* ptr1 = ptr0 + (N_NODES + 1);
    int* ptr2 = ptr1 + (N_NODES + 1);
    int* adj0 = ptr2 + (N_NODES + 1);
    int* adj1 = adj0 + NE;
    int* adj2 = adj1 + NE;
    int* fill = adj2 + NE;
    int* bsum = fill + N_NODES;

    const int* esrc[3] = {eic, eid, eit};
    int* ptrs[3] = {ptr0, ptr1, ptr2};
    int* adjs[3] = {adj0, adj1, adj2};

    dim3 b256(256);
    dim3 gE((NE + 255) / 256);

    // build 3 CSRs (dst-sorted)
    for (int s = 0; s < 3; ++s) {
        hipMemsetAsync(fill, 0, N_NODES * sizeof(int), stream);
        k_count<<<gE, b256, 0, stream>>>(esrc[s] + NE, fill);
        k_bsum<<<dim3(SCAN_G), b256, 0, stream>>>(fill, bsum);
        k_bscan<<<dim3(1), b256, 0, stream>>>(bsum, ptrs[s]);
        k_bwrite<<<dim3(SCAN_G), b256, 0, stream>>>(fill, bsum, ptrs[s], fill);
        k_build<<<gE, b256, 0, stream>>>(esrc[s], esrc[s] + NE, fill, adjs[s]);
    }

    const int L_set[7]  = {1, 0, 0, 2, 1, 0, 0};
    const int L_conv[7] = {0, 1, 1, 2, 3, 4, 4};
    const int L_norm[7] = {1, 1, 1, 0, 1, 1, 1};

    int nWaves = (N_NODES + 1) / 2;                 // 2 nodes per wave
    dim3 gAgg((nWaves + 3) / 4);                    // 4 waves/block
    dim3 gGemm((N_NODES + BM - 1) / BM);

    const float* hin = x;
    float* bufs[2] = {bufA, bufB};
    for (int L = 0; L < 7; ++L) {
        float* hout = bufs[L & 1];
        int s = L_set[L], c = L_conv[L];
        k_agg<<<gAgg, b256, 0, stream>>>(hin, ptrs[s], adjs[s], aggb);
        k_gemm<<<gGemm, b256, 0, stream>>>(aggb, hin, cW[c][0], cW[c][2], cW[c][1],
                                           hout, L_norm[L]);
        hin = hout;
    }

    hipMemsetAsync(gbuf, 0, (size_t)NG * H * sizeof(float), stream);
    k_pool<<<dim3((N_NODES + POOL_ROWS - 1) / POOL_ROWS), dim3(H), 0, stream>>>(
        hin, batch, gbuf);
    k_mlp<<<dim3(NG), dim3(H), 0, stream>>>(gbuf, l0_W, l0_b, l1_W, l1_b, hd_W, hd_b,
                                            outp);
}

// Round 3
// 1047.950 us; speedup vs baseline: 1.5455x; 1.0729x over previous
//
#include <hip/hip_runtime.h>
#include <hip/hip_bf16.h>

// ValueNet: 7x SAGEConv(mean) + global_add_pool + MLP head.
// N=50000 nodes, E=600000 edges/set, H=128, G=64 graphs. All fp32.

constexpr int N_NODES = 50000;
constexpr int NE      = 600000;
constexpr int H       = 128;
constexpr int NG      = 64;

// ---------------- CSR build (counting sort by dst) ----------------

__global__ void k_count(const int* __restrict__ dst, int* __restrict__ cnt) {
    int e = blockIdx.x * blockDim.x + threadIdx.x;
    if (e < NE) atomicAdd(&cnt[dst[e]], 1);
}

constexpr int SCAN_B = 256;
constexpr int SCAN_G = (N_NODES + SCAN_B - 1) / SCAN_B;  // 196

__global__ void k_bsum(const int* __restrict__ cnt, int* __restrict__ bsum) {
    __shared__ int sh[SCAN_B];
    int t = threadIdx.x;
    int i = blockIdx.x * SCAN_B + t;
    sh[t] = (i < N_NODES) ? cnt[i] : 0;
    __syncthreads();
    for (int off = SCAN_B / 2; off > 0; off >>= 1) {
        if (t < off) sh[t] += sh[t + off];
        __syncthreads();
    }
    if (t == 0) bsum[blockIdx.x] = sh[0];
}

__global__ void k_bscan(int* bsum, int* ptr) {  // 1 block
    __shared__ int sh[SCAN_B];
    int t = threadIdx.x;
    int v = (t < SCAN_G) ? bsum[t] : 0;
    sh[t] = v;
    __syncthreads();
    for (int off = 1; off < SCAN_B; off <<= 1) {
        int u = (t >= off) ? sh[t - off] : 0;
        __syncthreads();
        if (t >= off) sh[t] += u;
        __syncthreads();
    }
    if (t < SCAN_G) bsum[t] = sh[t] - v;
    if (t == 0) ptr[N_NODES] = sh[SCAN_B - 1];
}

__global__ void k_bwrite(const int* cnt, const int* __restrict__ boff,
                         int* __restrict__ ptr, int* fill) {
    __shared__ int sh[SCAN_B];
    int t = threadIdx.x;
    int i = blockIdx.x * SCAN_B + t;
    int v = (i < N_NODES) ? cnt[i] : 0;
    sh[t] = v;
    __syncthreads();
    for (int off = 1; off < SCAN_B; off <<= 1) {
        int u = (t >= off) ? sh[t - off] : 0;
        __syncthreads();
        if (t >= off) sh[t] += u;
        __syncthreads();
    }
    int excl = sh[t] - v + boff[blockIdx.x];
    if (i < N_NODES) {
        ptr[i]  = excl;
        fill[i] = excl;
    }
}

__global__ void k_build(const int* __restrict__ src, const int* __restrict__ dst,
                        int* __restrict__ fill, int* __restrict__ adj) {
    int e = blockIdx.x * blockDim.x + threadIdx.x;
    if (e < NE) {
        int pos = atomicAdd(&fill[dst[e]], 1);
        adj[pos] = src[e];
    }
}

// ---------------- mean aggregation ----------------
// One wave = 2 nodes (32 lanes each, float4/lane = full 512B row).
// Neighbor idx preloaded 32-wide, broadcast via shfl; gather 8-wide ILP.

__global__ __launch_bounds__(256) void k_agg(const float* __restrict__ h,
                                             const int* __restrict__ ptr,
                                             const int* __restrict__ adj,
                                             float* __restrict__ agg) {
    int wid  = (blockIdx.x * blockDim.x + threadIdx.x) >> 6;
    int lane = threadIdx.x & 63;
    int sl   = lane & 31;
    int node = wid * 2 + (lane >> 5);
    if (node >= N_NODES) return;
    int beg = ptr[node], end = ptr[node + 1];
    int deg = end - beg;
    const float* hrow = h + sl * 4;
    float ax = 0.f, ay = 0.f, az = 0.f, aw = 0.f;
    for (int base = 0; base < deg; base += 32) {
        int m = deg - base;
        if (m > 32) m = 32;
        int idx = (sl < m) ? adj[beg + base + sl] : 0;
        int j = 0;
        for (; j + 8 <= m; j += 8) {
            int n0 = __shfl(idx, j,     32);
            int n1 = __shfl(idx, j + 1, 32);
            int n2 = __shfl(idx, j + 2, 32);
            int n3 = __shfl(idx, j + 3, 32);
            int n4 = __shfl(idx, j + 4, 32);
            int n5 = __shfl(idx, j + 5, 32);
            int n6 = __shfl(idx, j + 6, 32);
            int n7 = __shfl(idx, j + 7, 32);
            float4 v0 = *(const float4*)(hrow + (size_t)n0 * H);
            float4 v1 = *(const float4*)(hrow + (size_t)n1 * H);
            float4 v2 = *(const float4*)(hrow + (size_t)n2 * H);
            float4 v3 = *(const float4*)(hrow + (size_t)n3 * H);
            float4 v4 = *(const float4*)(hrow + (size_t)n4 * H);
            float4 v5 = *(const float4*)(hrow + (size_t)n5 * H);
            float4 v6 = *(const float4*)(hrow + (size_t)n6 * H);
            float4 v7 = *(const float4*)(hrow + (size_t)n7 * H);
            ax += ((v0.x + v1.x) + (v2.x + v3.x)) + ((v4.x + v5.x) + (v6.x + v7.x));
            ay += ((v0.y + v1.y) + (v2.y + v3.y)) + ((v4.y + v5.y) + (v6.y + v7.y));
            az += ((v0.z + v1.z) + (v2.z + v3.z)) + ((v4.z + v5.z) + (v6.z + v7.z));
            aw += ((v0.w + v1.w) + (v2.w + v3.w)) + ((v4.w + v5.w) + (v6.w + v7.w));
        }
        for (; j + 4 <= m; j += 4) {
            int n0 = __shfl(idx, j,     32);
            int n1 = __shfl(idx, j + 1, 32);
            int n2 = __shfl(idx, j + 2, 32);
            int n3 = __shfl(idx, j + 3, 32);
            float4 v0 = *(const float4*)(hrow + (size_t)n0 * H);
            float4 v1 = *(const float4*)(hrow + (size_t)n1 * H);
            float4 v2 = *(const float4*)(hrow + (size_t)n2 * H);
            float4 v3 = *(const float4*)(hrow + (size_t)n3 * H);
            ax += (v0.x + v1.x) + (v2.x + v3.x);
            ay += (v0.y + v1.y) + (v2.y + v3.y);
            az += (v0.z + v1.z) + (v2.z + v3.z);
            aw += (v0.w + v1.w) + (v2.w + v3.w);
        }
        for (; j < m; ++j) {
            int n0 = __shfl(idx, j, 32);
            float4 v0 = *(const float4*)(hrow + (size_t)n0 * H);
            ax += v0.x; ay += v0.y; az += v0.z; aw += v0.w;
        }
    }
    float inv = 1.0f / (float)(deg > 1 ? deg : 1);
    *(float4*)(agg + (size_t)node * H + sl * 4) =
        make_float4(ax * inv, ay * inv, az * inv, aw * inv);
}

// ---------------- fused SAGE GEMM ----------------
// out = [agg, x] @ [Wl; Wr] + bl  (flattened K=256), optional L2-norm.
// Block 256 thr, tile 128x128, per-thread 8x8, register-prefetch next slab.

constexpr int BM = 128;
constexpr int KB = 8;

__global__ __launch_bounds__(256) void k_gemm(const float* __restrict__ Aagg,
                                              const float* __restrict__ Ax,
                                              const float* __restrict__ Wl,
                                              const float* __restrict__ Wr,
                                              const float* __restrict__ bl,
                                              float* __restrict__ out, int norm) {
    __shared__ float Ash[KB][BM + 8];
    __shared__ float Wsh[KB][H];

    int tid = threadIdx.x;
    int tc  = tid & 15;   // cols tc*8 .. +7
    int tr  = tid >> 4;   // rows tr*8 .. +7
    int rowBase = blockIdx.x * BM;

    float acc[8][8];
#pragma unroll
    for (int i = 0; i < 8; ++i)
#pragma unroll
        for (int j = 0; j < 8; ++j) acc[i][j] = 0.f;

    int lr = tid >> 1;        // 0..127  A-load row
    int lk = (tid & 1) * 4;   // 0 or 4  A-load k quad
    int grow = rowBase + lr;
    if (grow > N_NODES - 1) grow = N_NODES - 1;
    int wk = tid >> 5;        // 0..7  W-load k
    int wc = (tid & 31) * 4;  // W-load col

    const float* Asel[2] = {Aagg, Ax};
    const float* Wsel[2] = {Wl, Wr};

    float4 ga = *(const float4*)(Aagg + (size_t)grow * H + lk);
    float4 gw = *(const float4*)(Wl + (size_t)wk * H + wc);

    for (int kt = 0; kt < 2 * H; kt += KB) {
        __syncthreads();
        Ash[lk][lr]     = ga.x;
        Ash[lk + 1][lr] = ga.y;
        Ash[lk + 2][lr] = ga.z;
        Ash[lk + 3][lr] = ga.w;
        *(float4*)&Wsh[wk][wc] = gw;
        __syncthreads();
        int kn = kt + KB;
        if (kn < 2 * H) {
            const float* A = Asel[kn >> 7];
            const float* W = Wsel[kn >> 7];
            int ko = kn & (H - 1);
            ga = *(const float4*)(A + (size_t)grow * H + ko + lk);
            gw = *(const float4*)(W + (size_t)(ko + wk) * H + wc);
        }
#pragma unroll
        for (int kk = 0; kk < KB; ++kk) {
            float4 a0 = *(const float4*)&Ash[kk][tr * 8];
            float4 a1 = *(const float4*)&Ash[kk][tr * 8 + 4];
            float4 w0 = *(const float4*)&Wsh[kk][tc * 8];
            float4 w1 = *(const float4*)&Wsh[kk][tc * 8 + 4];
            float av[8] = {a0.x, a0.y, a0.z, a0.w, a1.x, a1.y, a1.z, a1.w};
            float wv[8] = {w0.x, w0.y, w0.z, w0.w, w1.x, w1.y, w1.z, w1.w};
#pragma unroll
            for (int i = 0; i < 8; ++i)
#pragma unroll
                for (int j = 0; j < 8; ++j) acc[i][j] += av[i] * wv[j];
        }
    }

    float bv[8];
#pragma unroll
    for (int j = 0; j < 8; ++j) bv[j] = bl[tc * 8 + j];
#pragma unroll
    for (int i = 0; i < 8; ++i)
#pragma unroll
        for (int j = 0; j < 8; ++j) acc[i][j] += bv[j];

    if (norm) {
#pragma unroll
        for (int i = 0; i < 8; ++i) {
            float ss = 0.f;
#pragma unroll
            for (int j = 0; j < 8; ++j) ss += acc[i][j] * acc[i][j];
#pragma unroll
            for (int m = 1; m < 16; m <<= 1) ss += __shfl_xor(ss, m, 16);
            float inv = 1.0f / fmaxf(sqrtf(ss), 1e-12f);
#pragma unroll
            for (int j = 0; j < 8; ++j) acc[i][j] *= inv;
        }
    }

#pragma unroll
    for (int i = 0; i < 8; ++i) {
        int r = rowBase + tr * 8 + i;
        if (r < N_NODES) {
            *(float4*)(out + (size_t)r * H + tc * 8) =
                make_float4(acc[i][0], acc[i][1], acc[i][2], acc[i][3]);
            *(float4*)(out + (size_t)r * H + tc * 8 + 4) =
                make_float4(acc[i][4], acc[i][5], acc[i][6], acc[i][7]);
        }
    }
}

// ---------------- global add pool (batch sorted) ----------------

constexpr int POOL_ROWS = 64;

__global__ void k_pool(const float* __restrict__ h, const int* __restrict__ batch,
                       float* __restrict__ g) {
    int col = threadIdx.x;  // 0..127
    int r0 = blockIdx.x * POOL_ROWS;
    int r1 = r0 + POOL_ROWS;
    if (r1 > N_NODES) r1 = N_NODES;
    if (r0 >= N_NODES) return;
    float acc = 0.f;
    int cur = batch[r0];
    int r = r0;
    for (; r + 4 <= r1; r += 4) {
        float v0 = h[(size_t)r * H + col];
        float v1 = h[(size_t)(r + 1) * H + col];
        float v2 = h[(size_t)(r + 2) * H + col];
        float v3 = h[(size_t)(r + 3) * H + col];
        int b3 = batch[r + 3];
        if (b3 == cur) {  // sorted => all 4 in current segment
            acc += (v0 + v1) + (v2 + v3);
        } else {
            int b0 = batch[r], b1 = batch[r + 1], b2 = batch[r + 2];
            if (b0 != cur) { atomicAdd(&g[cur * H + col], acc); acc = 0.f; cur = b0; }
            acc += v0;
            if (b1 != cur) { atomicAdd(&g[cur * H + col], acc); acc = 0.f; cur = b1; }
            acc += v1;
            if (b2 != cur) { atomicAdd(&g[cur * H + col], acc); acc = 0.f; cur = b2; }
            acc += v2;
            if (b3 != cur) { atomicAdd(&g[cur * H + col], acc); acc = 0.f; cur = b3; }
            acc += v3;
        }
    }
    for (; r < r1; ++r) {
        int b = batch[r];
        if (b != cur) { atomicAdd(&g[cur * H + col], acc); acc = 0.f; cur = b; }
        acc += h[(size_t)r * H + col];
    }
    atomicAdd(&g[cur * H + col], acc);
}

// ---------------- MLP head ----------------

__global__ void k_mlp(const float* __restrict__ g, const float* __restrict__ W0,
                      const float* __restrict__ b0, const float* __restrict__ W1,
                      const float* __restrict__ b1, const float* __restrict__ Wh,
                      const float* __restrict__ bh, float* __restrict__ out) {
    int gi = blockIdx.x;
    int t  = threadIdx.x;  // 0..127
    __shared__ float buf0[H];
    __shared__ float buf1[H];
    __shared__ float red[2];

    float acc = b0[t];
    for (int k = 0; k < H; ++k) acc += g[gi * H + k] * W0[k * H + t];
    buf0[t] = fmaxf(acc, 0.f);
    __syncthreads();

    acc = b1[t];
    for (int k = 0; k < H; ++k) acc += buf0[k] * W1[k * H + t];
    buf1[t] = fmaxf(acc, 0.f);
    __syncthreads();

    float p = buf1[t] * Wh[t];
    for (int m = 1; m < 64; m <<= 1) p += __shfl_xor(p, m, 64);
    if ((t & 63) == 0) red[t >> 6] = p;
    __syncthreads();
    if (t == 0) out[gi] = red[0] + red[1] + bh[0];
}

// ---------------- driver ----------------

extern "C" void kernel_launch(void* const* d_in, const int* in_sizes, int n_in,
                              void* d_out, int out_size, void* d_ws, size_t ws_size,
                              hipStream_t stream) {
    const float* x     = (const float*)d_in[0];
    const int*   eic   = (const int*)d_in[1];
    const int*   eid   = (const int*)d_in[2];
    const int*   eit   = (const int*)d_in[3];
    const int*   batch = (const int*)d_in[4];
    const float* cW[5][3];
    for (int c = 0; c < 5; ++c) {
        cW[c][0] = (const float*)d_in[5 + c * 3 + 0];  // Wl
        cW[c][1] = (const float*)d_in[5 + c * 3 + 1];  // bl
        cW[c][2] = (const float*)d_in[5 + c * 3 + 2];  // Wr
    }
    const float* l0_W = (const float*)d_in[20];
    const float* l0_b = (const float*)d_in[21];
    const float* l1_W = (const float*)d_in[22];
    const float* l1_b = (const float*)d_in[23];
    const float* hd_W = (const float*)d_in[24];
    const float* hd_b = (const float*)d_in[25];
    float* outp = (float*)d_out;

    const size_t NH = (size_t)N_NODES * H;
    float* bufA = (float*)d_ws;
    float* bufB = bufA + NH;
    float* aggb = bufB + NH;
    float* gbuf = aggb + NH;
    int* iws  = (int*)(gbuf + (size_t)NG * H);
    int* ptr0 = iws;
    int* ptr1 = ptr0 + (N_NODES + 1);
    int* ptr2 = ptr1 + (N_NODES + 1);
    int* adj0 = ptr2 + (N_NODES + 1);
    int* adj1 = adj0 + NE;
    int* adj2 = adj1 + NE;
    int* fill = adj2 + NE;
    int* bsum = fill + N_NODES;

    const int* esrc[3] = {eic, eid, eit};
    int* ptrs[3] = {ptr0, ptr1, ptr2};
    int* adjs[3] = {adj0, adj1, adj2};

    dim3 b256(256);
    dim3 gE((NE + 255) / 256);

    for (int s = 0; s < 3; ++s) {
        hipMemsetAsync(fill, 0, N_NODES * sizeof(int), stream);
        k_count<<<gE, b256, 0, stream>>>(esrc[s] + NE, fill);
        k_bsum<<<dim3(SCAN_G), b256, 0, stream>>>(fill, bsum);
        k_bscan<<<dim3(1), b256, 0, stream>>>(bsum, ptrs[s]);
        k_bwrite<<<dim3(SCAN_G), b256, 0, stream>>>(fill, bsum, ptrs[s], fill);
        k_build<<<gE, b256, 0, stream>>>(esrc[s], esrc[s] + NE, fill, adjs[s]);
    }

    const int L_set[7]  = {1, 0, 0, 2, 1, 0, 0};
    const int L_conv[7] = {0, 1, 1, 2, 3, 4, 4};
    const int L_norm[7] = {1, 1, 1, 0, 1, 1, 1};

    int nWaves = (N_NODES + 1) / 2;
    dim3 gAgg((nWaves + 3) / 4);
    dim3 gGemm((N_NODES + BM - 1) / BM);

    const float* hin = x;
    float* bufs[2] = {bufA, bufB};
    for (int L = 0; L < 7; ++L) {
        float* hout = bufs[L & 1];
        int s = L_set[L], c = L_conv[L];
        k_agg<<<gAgg, b256, 0, stream>>>(hin, ptrs[s], adjs[s], aggb);
        k_gemm<<<gGemm, b256, 0, stream>>>(aggb, hin, cW[c][0], cW[c][2], cW[c][1],
                                           hout, L_norm[L]);
        hin = hout;
    }

    hipMemsetAsync(gbuf, 0, (size_t)NG * H * sizeof(float), stream);
    k_pool<<<dim3((N_NODES + POOL_ROWS - 1) / POOL_ROWS), dim3(H), 0, stream>>>(
        hin, batch, gbuf);
    k_mlp<<<dim3(NG), dim3(H), 0, stream>>>(gbuf, l0_W, l0_b, l1_W, l1_b, hd_W, hd_b,
                                            outp);
}